// Round 2
// baseline (12725.768 us; speedup 1.0000x reference)
//
#include <hip/hip_runtime.h>
#include <hip/hip_bf16.h>

typedef __hip_bfloat16 bf16;

#define NV_   19
#define NB_   32
#define NN_   608
#define LL_   256
#define NE_   10944
#define NROWS (NN_*LL_)      // 155648
#define NTOT  (NROWS*64)     // 9961472
#define NBC   (NROWS*16)     // 2490368

__device__ __forceinline__ float b2f(bf16 x){ return __bfloat162float(x); }
__device__ __forceinline__ bf16 f2b(float x){ return __float2bfloat16(x); }
__device__ __forceinline__ float softplusf(float x){
  return fmaxf(x, 0.f) + log1pf(expf(-fabsf(x)));
}

// ---------- GCN norm precompute ----------
__global__ void k_deg(const int* __restrict__ ei, const float* __restrict__ ew,
                      float* __restrict__ deg){
  int i = blockIdx.x*256 + threadIdx.x;
  if (i < NN_) atomicAdd(&deg[i], 1.0f);              // self loop weight 1
  if (i < NE_) atomicAdd(&deg[ei[NE_ + i]], ew[i]);
}

__global__ void k_dinv(const float* __restrict__ deg, float* __restrict__ dinv,
                       float* __restrict__ M){
  int v = blockIdx.x*256 + threadIdx.x;
  if (v >= NN_) return;
  float r = rsqrtf(fmaxf(deg[v], 1e-12f));
  dinv[v] = r;
  int b = v / NV_, lv = v - b*NV_;
  M[(b*NV_ + lv)*NV_ + lv] = r*r;                     // self-loop norm
}

__global__ void k_edges(const int* __restrict__ ei, const float* __restrict__ ew,
                        const float* __restrict__ dinv, float* __restrict__ M){
  int i = blockIdx.x*256 + threadIdx.x;
  if (i >= NE_) return;
  int s = ei[i], d = ei[NE_ + i];
  float nrm = ew[i] * dinv[s] * dinv[d];
  int b = d / NV_;
  atomicAdd(&M[(b*NV_ + (d - b*NV_))*NV_ + (s - b*NV_)], nrm);
}

// ---------- fused projections: xz, x_dbl -> u, silu(z), dtr, B, C ----------
__global__ __launch_bounds__(256)
void k_proj(const float* __restrict__ xin, const float* __restrict__ inw,
            const float* __restrict__ xpw,
            bf16* __restrict__ u, bf16* __restrict__ zs,
            float* __restrict__ dtr, bf16* __restrict__ Bm, bf16* __restrict__ Cm){
  __shared__ float inT[32*129];   // [d][e], e<128, pad 129
  __shared__ float xpT[64*35];    // [e][j], j<34, pad 35
  __shared__ float xl[4][32];
  __shared__ float xh[4][64];
  int tid = threadIdx.x;
  for (int i = tid; i < 128*32; i += 256){
    int e = i >> 5, d = i & 31;
    inT[d*129 + e] = inw[i];
  }
  for (int i = tid; i < 34*64; i += 256){
    int j = i >> 6, e = i & 63;
    xpT[e*35 + j] = xpw[i];
  }
  int w = tid >> 6, lane = tid & 63;
  int r = blockIdx.x*4 + w;                 // r = node*256 + l
  if (lane < 32) xl[w][lane] = xin[r*32 + lane];
  __syncthreads();
  float a0 = 0.f, a1 = 0.f;
  #pragma unroll
  for (int d = 0; d < 32; d++){
    float xv = xl[w][d];
    a0 = fmaf(inT[d*129 + lane], xv, a0);
    a1 = fmaf(inT[d*129 + 64 + lane], xv, a1);
  }
  int node = r >> 8, l = r & 255;
  long ob = (long)l*NN_ + node;             // t-major layout
  u[ob*64 + lane] = f2b(a0);
  zs[ob*64 + lane] = f2b(a1 / (1.f + expf(-a1)));
  xh[w][lane] = a0;
  __syncthreads();
  if (lane < 34){
    float acc = 0.f;
    #pragma unroll
    for (int e = 0; e < 64; e++) acc = fmaf(xpT[e*35 + lane], xh[w][e], acc);
    if (lane < 2)       dtr[ob*2 + lane] = acc;
    else if (lane < 18) Bm[ob*16 + lane - 2] = f2b(acc);
    else                Cm[ob*16 + lane - 18] = f2b(acc);
  }
}

// ---------- uB = gcn_vec(u_t, gB) for all t (state-independent) ----------
__global__ __launch_bounds__(256)
void k_ub(const bf16* __restrict__ u, const float* __restrict__ gBw,
          const float* __restrict__ gBb, const float* __restrict__ Mg,
          bf16* __restrict__ uB){
  __shared__ float uL[19*64];
  __shared__ float wT[64*65];     // [d][e] pad 65
  __shared__ float hL[19*64];
  __shared__ float ML[361];
  int t = blockIdx.x >> 5, b = blockIdx.x & 31;
  int tid = threadIdx.x;
  const bf16* up = u + ((long)t*NN_ + b*19)*64;
  for (int i = tid; i < 1216; i += 256) uL[i] = b2f(up[i]);
  for (int i = tid; i < 4096; i += 256){
    int e = i >> 6, d = i & 63;
    wT[d*65 + e] = gBw[i];
  }
  for (int i = tid; i < 361; i += 256) ML[i] = Mg[b*361 + i];
  __syncthreads();
  int vg = tid >> 6, e = tid & 63;
  int nv = (vg < 3) ? 5 : 4;
  float h[5];
  #pragma unroll
  for (int k = 0; k < 5; k++){
    if (k < nv){
      int v = vg + 4*k;
      float acc = 0.f;
      #pragma unroll
      for (int d = 0; d < 64; d++) acc = fmaf(wT[d*65 + e], uL[v*64 + d], acc);
      h[k] = acc;
    }
  }
  #pragma unroll
  for (int k = 0; k < 5; k++) if (k < nv) hL[(vg + 4*k)*64 + e] = h[k];
  __syncthreads();
  float bb = gBb[e];
  float acc[5];
  #pragma unroll
  for (int k = 0; k < 5; k++) acc[k] = bb;
  for (int vp = 0; vp < 19; vp++){
    float hv = hL[vp*64 + e];
    #pragma unroll
    for (int k = 0; k < 5; k++)
      if (k < nv) acc[k] = fmaf(ML[(vg + 4*k)*19 + vp], hv, acc[k]);
  }
  bf16* op = uB + ((long)t*NN_ + b*19)*64;
  #pragma unroll
  for (int k = 0; k < 5; k++)
    if (k < nv) op[(vg + 4*k)*64 + e] = f2b(acc[k]);
}

// ---------- the sequential scan: block = (batch, n-pair) ----------
__global__ __launch_bounds__(512, 2)
void k_scan(const float* __restrict__ Mg, const float* __restrict__ dtrg,
            const bf16* __restrict__ uBg, const bf16* __restrict__ Bg,
            const bf16* __restrict__ Cg,
            const float* __restrict__ gAw, const float* __restrict__ gAb,
            const float* __restrict__ gCw, const float* __restrict__ gCb,
            const float* __restrict__ Alog, const float* __restrict__ dtw,
            const float* __restrict__ dtb, bf16* __restrict__ yp)
{
  __shared__ float lds[7657];
  float* sL = lds;            // 2432: state [half][v][e]
  float* hL = lds + 2432;     // 2432
  float* yL = lds + 4864;     // 2432
  float* ML = lds + 7296;     // 361
  int b = blockIdx.x >> 3, npair = blockIdx.x & 7;
  int tid = threadIdx.x;
  int half = tid >> 8;
  int rr = tid & 255;
  int vg = rr >> 6, e = rr & 63;
  int n = npair*2 + half;
  // stage gA_w / gC_w rows into registers via LDS scratch (coalesced global reads)
  float* scr = lds + 2432;    // reuse hL+yL (4864 floats >= 4096)
  float4 WA[16], WC[16];
  for (int i = tid; i < 4096; i += 512) scr[i] = gAw[i];
  __syncthreads();
  { const float4* rp = (const float4*)(scr + e*64);
    #pragma unroll
    for (int d4 = 0; d4 < 16; d4++) WA[d4] = rp[d4]; }
  __syncthreads();
  for (int i = tid; i < 4096; i += 512) scr[i] = gCw[i];
  __syncthreads();
  { const float4* rp = (const float4*)(scr + e*64);
    #pragma unroll
    for (int d4 = 0; d4 < 16; d4++) WC[d4] = rp[d4]; }
  __syncthreads();
  for (int i = tid; i < 361; i += 512) ML[i] = Mg[b*361 + i];
  for (int i = tid; i < 2432; i += 512) sL[i] = 0.f;
  __syncthreads();

  float An = -expf(Alog[e*16 + n]);
  float w0 = dtw[e*2 + 0], w1 = dtw[e*2 + 1], db = dtb[e];
  float bA = gAb[e], bC = gCb[e];
  int nv = (vg < 3) ? 5 : 4;
  int nodeBase = b*19;

  for (int t = 0; t < 256; t++){
    // prefetch this step's inputs (consumed after ~1.3k cycles of phase A)
    float dtx[5], uBv[5], Bv[5], Cv[5];
    #pragma unroll
    for (int k = 0; k < 5; k++){
      if (k < nv){
        long base = (long)t*NN_ + nodeBase + vg + 4*k;
        float r0 = dtrg[base*2], r1 = dtrg[base*2 + 1];
        dtx[k] = fmaf(r0, w0, fmaf(r1, w1, db));
        uBv[k] = b2f(uBg[base*64 + e]);
        Bv[k]  = b2f(Bg[base*16 + n]);
        Cv[k]  = b2f(Cg[base*16 + n]);
      }
    }
    // phase A: h = gA_w . s  (s_lds broadcast float4 reads, weights in regs)
    float h[5];
    #pragma unroll
    for (int k = 0; k < 5; k++){
      if (k < nv){
        const float4* sv = (const float4*)(sL + (half*19 + vg + 4*k)*64);
        float4 a = {0.f,0.f,0.f,0.f};
        #pragma unroll
        for (int d4 = 0; d4 < 16; d4++){
          float4 s4 = sv[d4];
          a.x = fmaf(WA[d4].x, s4.x, a.x);
          a.y = fmaf(WA[d4].y, s4.y, a.y);
          a.z = fmaf(WA[d4].z, s4.z, a.z);
          a.w = fmaf(WA[d4].w, s4.w, a.w);
        }
        h[k] = (a.x + a.y) + (a.z + a.w);
      }
    }
    #pragma unroll
    for (int k = 0; k < 5; k++) if (k < nv) hL[half*1216 + (vg + 4*k)*64 + e] = h[k];
    __syncthreads();
    // agg A (register-local over v', M broadcast) + state update
    float acc[5];
    #pragma unroll
    for (int k = 0; k < 5; k++) acc[k] = bA;
    for (int vp = 0; vp < 19; vp++){
      float hv = hL[half*1216 + vp*64 + e];
      #pragma unroll
      for (int k = 0; k < 5; k++)
        if (k < nv) acc[k] = fmaf(ML[(vg + 4*k)*19 + vp], hv, acc[k]);
    }
    #pragma unroll
    for (int k = 0; k < 5; k++){
      if (k < nv){
        float dt = softplusf(dtx[k]);
        float dA = expf(dt * An);
        float snew = fmaf(acc[k], dA, uBv[k] * dt * Bv[k]);
        sL[half*1216 + (vg + 4*k)*64 + e] = snew;
      }
    }
    __syncthreads();
    // phase C: gC on s_new
    #pragma unroll
    for (int k = 0; k < 5; k++){
      if (k < nv){
        const float4* sv = (const float4*)(sL + (half*19 + vg + 4*k)*64);
        float4 a = {0.f,0.f,0.f,0.f};
        #pragma unroll
        for (int d4 = 0; d4 < 16; d4++){
          float4 s4 = sv[d4];
          a.x = fmaf(WC[d4].x, s4.x, a.x);
          a.y = fmaf(WC[d4].y, s4.y, a.y);
          a.z = fmaf(WC[d4].z, s4.z, a.z);
          a.w = fmaf(WC[d4].w, s4.w, a.w);
        }
        h[k] = (a.x + a.y) + (a.z + a.w);
      }
    }
    #pragma unroll
    for (int k = 0; k < 5; k++) if (k < nv) hL[half*1216 + (vg + 4*k)*64 + e] = h[k];
    __syncthreads();
    #pragma unroll
    for (int k = 0; k < 5; k++) acc[k] = bC;
    for (int vp = 0; vp < 19; vp++){
      float hv = hL[half*1216 + vp*64 + e];
      #pragma unroll
      for (int k = 0; k < 5; k++)
        if (k < nv) acc[k] = fmaf(ML[(vg + 4*k)*19 + vp], hv, acc[k]);
    }
    #pragma unroll
    for (int k = 0; k < 5; k++)
      if (k < nv) yL[half*1216 + (vg + 4*k)*64 + e] = acc[k] * Cv[k];
    __syncthreads();
    if (half == 0){
      #pragma unroll
      for (int k = 0; k < 5; k++){
        if (k < nv){
          int v = vg + 4*k;
          float tot = yL[v*64 + e] + yL[1216 + v*64 + e];
          yp[(((long)npair*256 + t)*NN_ + nodeBase + v)*64 + e] = f2b(tot);
        }
      }
    }
  }
}

// ---------- reduce partials, gate, out_proj ----------
__global__ __launch_bounds__(256)
void k_final(const bf16* __restrict__ yp, const bf16* __restrict__ u,
             const bf16* __restrict__ zs, const float* __restrict__ Dp,
             const float* __restrict__ ow, float* __restrict__ out)
{
  __shared__ float oT[64*33];   // [e][o] pad 33
  __shared__ float yl[4][64];
  int tid = threadIdx.x;
  for (int i = tid; i < 32*64; i += 256){
    int o = i >> 6, e = i & 63;
    oT[e*33 + o] = ow[i];
  }
  int w = tid >> 6, lane = tid & 63;
  long r = (long)blockIdx.x*4 + w;        // r = t*608 + node
  long base = r*64;
  float y = Dp[lane] * b2f(u[base + lane]);
  #pragma unroll
  for (int p = 0; p < 8; p++) y += b2f(yp[(long)p*NTOT + base + lane]);
  y *= b2f(zs[base + lane]);
  yl[w][lane] = y;
  __syncthreads();
  if (lane < 32){
    float acc = 0.f;
    #pragma unroll
    for (int e = 0; e < 64; e++) acc = fmaf(oT[e*33 + lane], yl[w][e], acc);
    int t = (int)(r / NN_), node = (int)(r - (long)t*NN_);
    out[((long)node*256 + t)*32 + lane] = acc;
  }
}

extern "C" void kernel_launch(void* const* d_in, const int* in_sizes, int n_in,
                              void* d_out, int out_size, void* d_ws, size_t ws_size,
                              hipStream_t stream)
{
  (void)in_sizes; (void)n_in; (void)out_size; (void)ws_size;
  const float* xin = (const float*)d_in[0];
  const int*   ei  = (const int*)  d_in[1];
  const float* ew  = (const float*)d_in[2];
  const float* inw = (const float*)d_in[3];
  const float* xpw = (const float*)d_in[4];
  const float* dtw = (const float*)d_in[5];
  const float* dtb = (const float*)d_in[6];
  const float* Alog= (const float*)d_in[7];
  const float* Dp  = (const float*)d_in[8];
  const float* ow  = (const float*)d_in[9];
  const float* gAw = (const float*)d_in[10];
  const float* gAb = (const float*)d_in[11];
  const float* gBw = (const float*)d_in[12];
  const float* gBb = (const float*)d_in[13];
  const float* gCw = (const float*)d_in[14];
  const float* gCb = (const float*)d_in[15];
  float* out = (float*)d_out;

  float* Mg   = (float*)d_ws;            // 11552 f32
  float* deg  = Mg + 11552;              // 608
  float* dinv = deg + 608;               // 608
  float* dtr  = dinv + 608;              // 2*NROWS f32
  bf16*  u    = (bf16*)(dtr + 2*NROWS);  // NTOT bf16
  bf16*  zs   = u + NTOT;
  bf16*  uB   = zs + NTOT;
  bf16*  Bm   = uB + NTOT;               // NBC
  bf16*  Cm   = Bm + NBC;                // NBC
  bf16*  yp   = Cm + NBC;                // 8*NTOT   (total ws ~230 MB)

  hipMemsetAsync(d_ws, 0, (11552 + 608)*sizeof(float), stream);  // M + deg
  k_deg  <<<(NE_ + 255)/256, 256, 0, stream>>>(ei, ew, deg);
  k_dinv <<<(NN_ + 255)/256, 256, 0, stream>>>(deg, dinv, Mg);
  k_edges<<<(NE_ + 255)/256, 256, 0, stream>>>(ei, ew, dinv, Mg);
  k_proj <<<NROWS/4, 256, 0, stream>>>(xin, inw, xpw, u, zs, dtr, Bm, Cm);
  k_ub   <<<LL_*NB_, 256, 0, stream>>>(u, gBw, gBb, Mg, uB);
  k_scan <<<NB_*8, 512, 0, stream>>>(Mg, dtr, uB, Bm, Cm, gAw, gAb, gCw, gCb,
                                     Alog, dtw, dtb, yp);
  k_final<<<NROWS/4, 256, 0, stream>>>(yp, u, zs, Dp, ow, out);
}

// Round 3
// 12713.065 us; speedup vs baseline: 1.0010x; 1.0010x over previous
//
#include <hip/hip_runtime.h>
#include <hip/hip_bf16.h>

typedef __hip_bfloat16 bf16;

#define NV_   19
#define NB_   32
#define NN_   608
#define LL_   256
#define NE_   10944
#define NROWS (NN_*LL_)      // 155648
#define NTOT  (NROWS*64)     // 9961472
#define NBC   (NROWS*16)     // 2490368

__device__ __forceinline__ float b2f(bf16 x){ return __bfloat162float(x); }
__device__ __forceinline__ bf16 f2b(float x){ return __float2bfloat16(x); }
__device__ __forceinline__ float softplusf(float x){
  return fmaxf(x, 0.f) + log1pf(expf(-fabsf(x)));
}

// ---------- GCN norm precompute ----------
__global__ void k_deg(const int* __restrict__ ei, const float* __restrict__ ew,
                      float* __restrict__ deg){
  int i = blockIdx.x*256 + threadIdx.x;
  if (i < NN_) atomicAdd(&deg[i], 1.0f);              // self loop weight 1
  if (i < NE_) atomicAdd(&deg[ei[NE_ + i]], ew[i]);
}

__global__ void k_dinv(const float* __restrict__ deg, float* __restrict__ dinv,
                       float* __restrict__ M){
  int v = blockIdx.x*256 + threadIdx.x;
  if (v >= NN_) return;
  float r = rsqrtf(fmaxf(deg[v], 1e-12f));
  dinv[v] = r;
  int b = v / NV_, lv = v - b*NV_;
  M[(b*NV_ + lv)*NV_ + lv] = r*r;                     // self-loop norm
}

__global__ void k_edges(const int* __restrict__ ei, const float* __restrict__ ew,
                        const float* __restrict__ dinv, float* __restrict__ M){
  int i = blockIdx.x*256 + threadIdx.x;
  if (i >= NE_) return;
  int s = ei[i], d = ei[NE_ + i];
  float nrm = ew[i] * dinv[s] * dinv[d];
  int b = d / NV_;
  atomicAdd(&M[(b*NV_ + (d - b*NV_))*NV_ + (s - b*NV_)], nrm);
}

// ---------- fused projections: xz, x_dbl -> u, silu(z), dtr, B, C ----------
__global__ __launch_bounds__(256)
void k_proj(const float* __restrict__ xin, const float* __restrict__ inw,
            const float* __restrict__ xpw,
            bf16* __restrict__ u, bf16* __restrict__ zs,
            float* __restrict__ dtr, bf16* __restrict__ Bm, bf16* __restrict__ Cm){
  __shared__ float inT[32*129];   // [d][e], e<128, pad 129
  __shared__ float xpT[64*35];    // [e][j], j<34, pad 35
  __shared__ float xl[4][32];
  __shared__ float xh[4][64];
  int tid = threadIdx.x;
  for (int i = tid; i < 128*32; i += 256){
    int e = i >> 5, d = i & 31;
    inT[d*129 + e] = inw[i];
  }
  for (int i = tid; i < 34*64; i += 256){
    int j = i >> 6, e = i & 63;
    xpT[e*35 + j] = xpw[i];
  }
  int w = tid >> 6, lane = tid & 63;
  int r = blockIdx.x*4 + w;                 // r = node*256 + l
  if (lane < 32) xl[w][lane] = xin[r*32 + lane];
  __syncthreads();
  float a0 = 0.f, a1 = 0.f;
  #pragma unroll
  for (int d = 0; d < 32; d++){
    float xv = xl[w][d];
    a0 = fmaf(inT[d*129 + lane], xv, a0);
    a1 = fmaf(inT[d*129 + 64 + lane], xv, a1);
  }
  int node = r >> 8, l = r & 255;
  long ob = (long)l*NN_ + node;             // t-major layout
  u[ob*64 + lane] = f2b(a0);
  zs[ob*64 + lane] = f2b(a1 / (1.f + expf(-a1)));
  xh[w][lane] = a0;
  __syncthreads();
  if (lane < 34){
    float acc = 0.f;
    #pragma unroll
    for (int e = 0; e < 64; e++) acc = fmaf(xpT[e*35 + lane], xh[w][e], acc);
    if (lane < 2)       dtr[ob*2 + lane] = acc;
    else if (lane < 18) Bm[ob*16 + lane - 2] = f2b(acc);
    else                Cm[ob*16 + lane - 18] = f2b(acc);
  }
}

// ---------- uB = gcn_vec(u_t, gB) for all t (state-independent) ----------
__global__ __launch_bounds__(256)
void k_ub(const bf16* __restrict__ u, const float* __restrict__ gBw,
          const float* __restrict__ gBb, const float* __restrict__ Mg,
          bf16* __restrict__ uB){
  __shared__ float uL[19*64];
  __shared__ float wT[64*65];     // [d][e] pad 65
  __shared__ float hL[19*64];
  __shared__ float ML[361];
  int t = blockIdx.x >> 5, b = blockIdx.x & 31;
  int tid = threadIdx.x;
  const bf16* up = u + ((long)t*NN_ + b*19)*64;
  for (int i = tid; i < 1216; i += 256) uL[i] = b2f(up[i]);
  for (int i = tid; i < 4096; i += 256){
    int e = i >> 6, d = i & 63;
    wT[d*65 + e] = gBw[i];
  }
  for (int i = tid; i < 361; i += 256) ML[i] = Mg[b*361 + i];
  __syncthreads();
  int vg = tid >> 6, e = tid & 63;
  int nv = (vg < 3) ? 5 : 4;
  float h[5];
  #pragma unroll
  for (int k = 0; k < 5; k++){
    if (k < nv){
      int v = vg + 4*k;
      float acc = 0.f;
      #pragma unroll
      for (int d = 0; d < 64; d++) acc = fmaf(wT[d*65 + e], uL[v*64 + d], acc);
      h[k] = acc;
    }
  }
  #pragma unroll
  for (int k = 0; k < 5; k++) if (k < nv) hL[(vg + 4*k)*64 + e] = h[k];
  __syncthreads();
  float bb = gBb[e];
  float acc[5];
  #pragma unroll
  for (int k = 0; k < 5; k++) acc[k] = bb;
  for (int vp = 0; vp < 19; vp++){
    float hv = hL[vp*64 + e];
    #pragma unroll
    for (int k = 0; k < 5; k++)
      if (k < nv) acc[k] = fmaf(ML[(vg + 4*k)*19 + vp], hv, acc[k]);
  }
  bf16* op = uB + ((long)t*NN_ + b*19)*64;
  #pragma unroll
  for (int k = 0; k < 5; k++)
    if (k < nv) op[(vg + 4*k)*64 + e] = f2b(acc[k]);
}

// ---------- the sequential scan: block = (batch, n-pair) ----------
// NOTE: __launch_bounds__(512, 1): grid is 256 blocks on 256 CUs, so >1
// block/CU is impossible — but the (512,2) variant capped VGPRs at 128 and
// spilled ~256 f32/thread to scratch (rocprof R2: 34 GB traffic, VALUBusy 12%).
__global__ __launch_bounds__(512, 1)
void k_scan(const float* __restrict__ Mg, const float* __restrict__ dtrg,
            const bf16* __restrict__ uBg, const bf16* __restrict__ Bg,
            const bf16* __restrict__ Cg,
            const float* __restrict__ gAw, const float* __restrict__ gAb,
            const float* __restrict__ gCw, const float* __restrict__ gCb,
            const float* __restrict__ Alog, const float* __restrict__ dtw,
            const float* __restrict__ dtb, bf16* __restrict__ yp)
{
  __shared__ float lds[7657];
  float* sL = lds;            // 2432: state [half][v][e]
  float* hL = lds + 2432;     // 2432
  float* yL = lds + 4864;     // 2432
  float* ML = lds + 7296;     // 361
  int b = blockIdx.x >> 3, npair = blockIdx.x & 7;
  int tid = threadIdx.x;
  int half = tid >> 8;
  int rr = tid & 255;
  int vg = rr >> 6, e = rr & 63;
  int n = npair*2 + half;
  // stage gA_w / gC_w rows into registers via LDS scratch (coalesced global reads)
  float* scr = lds + 2432;    // reuse hL+yL (4864 floats >= 4096)
  float4 WA[16], WC[16];
  for (int i = tid; i < 4096; i += 512) scr[i] = gAw[i];
  __syncthreads();
  { const float4* rp = (const float4*)(scr + e*64);
    #pragma unroll
    for (int d4 = 0; d4 < 16; d4++) WA[d4] = rp[d4]; }
  __syncthreads();
  for (int i = tid; i < 4096; i += 512) scr[i] = gCw[i];
  __syncthreads();
  { const float4* rp = (const float4*)(scr + e*64);
    #pragma unroll
    for (int d4 = 0; d4 < 16; d4++) WC[d4] = rp[d4]; }
  __syncthreads();
  for (int i = tid; i < 361; i += 512) ML[i] = Mg[b*361 + i];
  for (int i = tid; i < 2432; i += 512) sL[i] = 0.f;
  __syncthreads();

  float An = -expf(Alog[e*16 + n]);
  float w0 = dtw[e*2 + 0], w1 = dtw[e*2 + 1], db = dtb[e];
  float bA = gAb[e], bC = gCb[e];
  int nv = (vg < 3) ? 5 : 4;
  int nodeBase = b*19;

  for (int t = 0; t < 256; t++){
    // prefetch this step's inputs (consumed after ~1.3k cycles of phase A)
    float dtx[5], uBv[5], Bv[5], Cv[5];
    #pragma unroll
    for (int k = 0; k < 5; k++){
      if (k < nv){
        long base = (long)t*NN_ + nodeBase + vg + 4*k;
        float r0 = dtrg[base*2], r1 = dtrg[base*2 + 1];
        dtx[k] = fmaf(r0, w0, fmaf(r1, w1, db));
        uBv[k] = b2f(uBg[base*64 + e]);
        Bv[k]  = b2f(Bg[base*16 + n]);
        Cv[k]  = b2f(Cg[base*16 + n]);
      }
    }
    // phase A: h = gA_w . s  (s_lds broadcast float4 reads, weights in regs)
    float h[5];
    #pragma unroll
    for (int k = 0; k < 5; k++){
      if (k < nv){
        const float4* sv = (const float4*)(sL + (half*19 + vg + 4*k)*64);
        float4 a = {0.f,0.f,0.f,0.f};
        #pragma unroll
        for (int d4 = 0; d4 < 16; d4++){
          float4 s4 = sv[d4];
          a.x = fmaf(WA[d4].x, s4.x, a.x);
          a.y = fmaf(WA[d4].y, s4.y, a.y);
          a.z = fmaf(WA[d4].z, s4.z, a.z);
          a.w = fmaf(WA[d4].w, s4.w, a.w);
        }
        h[k] = (a.x + a.y) + (a.z + a.w);
      }
    }
    #pragma unroll
    for (int k = 0; k < 5; k++) if (k < nv) hL[half*1216 + (vg + 4*k)*64 + e] = h[k];
    __syncthreads();
    // agg A (register-local over v', M broadcast) + state update
    float acc[5];
    #pragma unroll
    for (int k = 0; k < 5; k++) acc[k] = bA;
    for (int vp = 0; vp < 19; vp++){
      float hv = hL[half*1216 + vp*64 + e];
      #pragma unroll
      for (int k = 0; k < 5; k++)
        if (k < nv) acc[k] = fmaf(ML[(vg + 4*k)*19 + vp], hv, acc[k]);
    }
    #pragma unroll
    for (int k = 0; k < 5; k++){
      if (k < nv){
        float dt = softplusf(dtx[k]);
        float dA = expf(dt * An);
        float snew = fmaf(acc[k], dA, uBv[k] * dt * Bv[k]);
        sL[half*1216 + (vg + 4*k)*64 + e] = snew;
      }
    }
    __syncthreads();
    // phase C: gC on s_new
    #pragma unroll
    for (int k = 0; k < 5; k++){
      if (k < nv){
        const float4* sv = (const float4*)(sL + (half*19 + vg + 4*k)*64);
        float4 a = {0.f,0.f,0.f,0.f};
        #pragma unroll
        for (int d4 = 0; d4 < 16; d4++){
          float4 s4 = sv[d4];
          a.x = fmaf(WC[d4].x, s4.x, a.x);
          a.y = fmaf(WC[d4].y, s4.y, a.y);
          a.z = fmaf(WC[d4].z, s4.z, a.z);
          a.w = fmaf(WC[d4].w, s4.w, a.w);
        }
        h[k] = (a.x + a.y) + (a.z + a.w);
      }
    }
    #pragma unroll
    for (int k = 0; k < 5; k++) if (k < nv) hL[half*1216 + (vg + 4*k)*64 + e] = h[k];
    __syncthreads();
    #pragma unroll
    for (int k = 0; k < 5; k++) acc[k] = bC;
    for (int vp = 0; vp < 19; vp++){
      float hv = hL[half*1216 + vp*64 + e];
      #pragma unroll
      for (int k = 0; k < 5; k++)
        if (k < nv) acc[k] = fmaf(ML[(vg + 4*k)*19 + vp], hv, acc[k]);
    }
    #pragma unroll
    for (int k = 0; k < 5; k++)
      if (k < nv) yL[half*1216 + (vg + 4*k)*64 + e] = acc[k] * Cv[k];
    __syncthreads();
    if (half == 0){
      #pragma unroll
      for (int k = 0; k < 5; k++){
        if (k < nv){
          int v = vg + 4*k;
          float tot = yL[v*64 + e] + yL[1216 + v*64 + e];
          yp[(((long)npair*256 + t)*NN_ + nodeBase + v)*64 + e] = f2b(tot);
        }
      }
    }
  }
}

// ---------- reduce partials, gate, out_proj ----------
__global__ __launch_bounds__(256)
void k_final(const bf16* __restrict__ yp, const bf16* __restrict__ u,
             const bf16* __restrict__ zs, const float* __restrict__ Dp,
             const float* __restrict__ ow, float* __restrict__ out)
{
  __shared__ float oT[64*33];   // [e][o] pad 33
  __shared__ float yl[4][64];
  int tid = threadIdx.x;
  for (int i = tid; i < 32*64; i += 256){
    int o = i >> 6, e = i & 63;
    oT[e*33 + o] = ow[i];
  }
  int w = tid >> 6, lane = tid & 63;
  long r = (long)blockIdx.x*4 + w;        // r = t*608 + node
  long base = r*64;
  float y = Dp[lane] * b2f(u[base + lane]);
  #pragma unroll
  for (int p = 0; p < 8; p++) y += b2f(yp[(long)p*NTOT + base + lane]);
  y *= b2f(zs[base + lane]);
  yl[w][lane] = y;
  __syncthreads();
  if (lane < 32){
    float acc = 0.f;
    #pragma unroll
    for (int e = 0; e < 64; e++) acc = fmaf(oT[e*33 + lane], yl[w][e], acc);
    int t = (int)(r / NN_), node = (int)(r - (long)t*NN_);
    out[((long)node*256 + t)*32 + lane] = acc;
  }
}

extern "C" void kernel_launch(void* const* d_in, const int* in_sizes, int n_in,
                              void* d_out, int out_size, void* d_ws, size_t ws_size,
                              hipStream_t stream)
{
  (void)in_sizes; (void)n_in; (void)out_size; (void)ws_size;
  const float* xin = (const float*)d_in[0];
  const int*   ei  = (const int*)  d_in[1];
  const float* ew  = (const float*)d_in[2];
  const float* inw = (const float*)d_in[3];
  const float* xpw = (const float*)d_in[4];
  const float* dtw = (const float*)d_in[5];
  const float* dtb = (const float*)d_in[6];
  const float* Alog= (const float*)d_in[7];
  const float* Dp  = (const float*)d_in[8];
  const float* ow  = (const float*)d_in[9];
  const float* gAw = (const float*)d_in[10];
  const float* gAb = (const float*)d_in[11];
  const float* gBw = (const float*)d_in[12];
  const float* gBb = (const float*)d_in[13];
  const float* gCw = (const float*)d_in[14];
  const float* gCb = (const float*)d_in[15];
  float* out = (float*)d_out;

  float* Mg   = (float*)d_ws;            // 11552 f32
  float* deg  = Mg + 11552;              // 608
  float* dinv = deg + 608;               // 608
  float* dtr  = dinv + 608;              // 2*NROWS f32
  bf16*  u    = (bf16*)(dtr + 2*NROWS);  // NTOT bf16
  bf16*  zs   = u + NTOT;
  bf16*  uB   = zs + NTOT;
  bf16*  Bm   = uB + NTOT;               // NBC
  bf16*  Cm   = Bm + NBC;                // NBC
  bf16*  yp   = Cm + NBC;                // 8*NTOT   (total ws ~230 MB)

  hipMemsetAsync(d_ws, 0, (11552 + 608)*sizeof(float), stream);  // M + deg
  k_deg  <<<(NE_ + 255)/256, 256, 0, stream>>>(ei, ew, deg);
  k_dinv <<<(NN_ + 255)/256, 256, 0, stream>>>(deg, dinv, Mg);
  k_edges<<<(NE_ + 255)/256, 256, 0, stream>>>(ei, ew, dinv, Mg);
  k_proj <<<NROWS/4, 256, 0, stream>>>(xin, inw, xpw, u, zs, dtr, Bm, Cm);
  k_ub   <<<LL_*NB_, 256, 0, stream>>>(u, gBw, gBb, Mg, uB);
  k_scan <<<NB_*8, 512, 0, stream>>>(Mg, dtr, uB, Bm, Cm, gAw, gAb, gCw, gCb,
                                     Alog, dtw, dtb, yp);
  k_final<<<NROWS/4, 256, 0, stream>>>(yp, u, zs, Dp, ow, out);
}